// Round 8
// baseline (1935.402 us; speedup 1.0000x reference)
//
#include <hip/hip_runtime.h>

// Viterbi / CRF decode: B=32, S=512, T=128.
// R8: chain-multiplexed exchange hiding. 64 blocks = 8 slices x 8 groups;
// each block runs slice k of FOUR batches {q, q+8, q+16, q+24} (group q).
// Per step: 4 compute waves compute+publish all 4 chains back-to-back
// (~600 cyc), so by the time the 2 dedicated poller waves spin on the
// remote partials, most of the cross-CU RT has already elapsed -> exchange
// latency is hidden behind the other chains' work. Poller waves issue NO
// other VMEM, so their per-retry vmcnt(0) is clean (R4 flaw fixed).
//
// Exchange protocol (proven in R4/R7): pub[b][parity][slice][j] u64 keys
// {flip(val):32 | (127-i):8 | s:24}; unsigned max == reference first-max
// (exact value, ties -> smallest i); tag self-validates; parity slots safe
// by the publish-after-consume chaining argument; stale replay tags carry
// bitwise-identical values (deterministic recurrence).
// Compute mapping per wave w (cols w*32..w*32+31): lane = rr*8+cc,
// rows {2rr,2rr+1} of slice k, cols {4cc..4cc+3}; exact ref fp order
// (fs[i]+t1[j])+t0[i,j], ascending-i strict >; in-wave shfl_xor(8,16,32)
// u64-max butterfly; rr==0 lanes publish. Poller lane = lr*8+sl: polls
// slice sl, rows k*16+lr and +8; shfl_xor(1,2,4) merge; sl==0 writes
// fs_lds (double-buffered by parity) + bp byte.

constexpr int S   = 512;
constexpr int T   = 128;
constexpr int NSL = 8;        // i-slices per batch
constexpr int NQ  = 8;        // batch groups
constexpr int C   = 4;        // chains (batches) per block

using u64 = unsigned long long;
using u32 = unsigned int;

__device__ __forceinline__ void bar_lds() {
    asm volatile("s_waitcnt lgkmcnt(0)" ::: "memory");
    __builtin_amdgcn_s_barrier();
}
__device__ __forceinline__ u32 flipf(u32 u)   { return u ^ (0x80000000u | (u32)((int)u >> 31)); }
__device__ __forceinline__ u32 unflipf(u32 y) { return y ^ (0x80000000u | ~(u32)((int)y >> 31)); }
__device__ __forceinline__ u64 aload(const u64* p) {
    return __hip_atomic_load(p, __ATOMIC_RELAXED, __HIP_MEMORY_SCOPE_AGENT);
}
__device__ __forceinline__ void astore(u64* p, u64 v) {
    __hip_atomic_store(p, v, __ATOMIC_RELAXED, __HIP_MEMORY_SCOPE_AGENT);
}

__global__ __launch_bounds__(384, 1)
void viterbi_fwd4(const float* __restrict__ c0, const float* __restrict__ c1,
                  const int* __restrict__ sofp,
                  u64* __restrict__ pub,           // [32][2][NSL][T]
                  unsigned char* __restrict__ bp)  // [32][S][T]
{
    __shared__ float fs_lds[2][C][16];   // parity-double-buffered fs per chain

    const int g   = blockIdx.x;
    const int k   = g >> 3;              // slice 0..7
    const int q   = g & 7;               // group 0..7 (XCD = g%8 = q)
    const int tid = (int)threadIdx.x;
    const int wv  = tid >> 6;            // 0..3 compute, 4..5 pollers
    const int ln  = tid & 63;

    // ---- init fs (parity 0): fs0[j] = c0[b,0,sof,j] * c1[b,0,j] ----
    if (tid < C * 16) {
        const int c  = tid >> 4;
        const int lr = tid & 15;
        const int b  = q + NQ * c;
        const float* c0b = c0 + (size_t)b * (S + 1) * T * T;
        const float* c1b = c1 + (size_t)b * (S + 1) * T;
        const int sof = sofp[0];
        fs_lds[0][c][lr] = c0b[(size_t)sof * T + k * 16 + lr] * c1b[k * 16 + lr];
    }
    bar_lds();

    if (wv < 4) {
        // ================= compute waves =================
        const int rr   = (ln >> 3) & 7;          // row-pair 0..7
        const int cc   = ln & 7;                 // col-quad 0..7
        const int col0 = wv * 32 + cc * 4;       // 4 owned cols
        const int iA   = k * 16 + 2 * rr;        // global row (ascending pair)
        const u32 tie24A = (u32)(127 - iA) << 24;

        // per-chain bases
        const float* c0b[1]; (void)c0b;
        #define DECL_CHAIN(c)                                                   \
            const float* c0b##c = c0 + (size_t)(q + NQ * c) * (S + 1) * T * T;  \
            const float* c1b##c = c1 + (size_t)(q + NQ * c) * (S + 1) * T;      \
            const float* pA##c = c0b##c + (size_t)T * T + (size_t)iA * T + col0;\
            const float* qA##c = c1b##c + T + col0;                             \
            const float* pB##c = pA##c + T * T;                                 \
            const float* qB##c = qA##c + T;                                     \
            float4 A0##c = *(const float4*)(pA##c);                             \
            float4 A1##c = *(const float4*)(pA##c + T);                         \
            float4 At##c = *(const float4*)(qA##c);                             \
            float4 B0##c = *(const float4*)(pB##c);                             \
            float4 B1##c = *(const float4*)(pB##c + T);                         \
            float4 Bt##c = *(const float4*)(qB##c);                             \
            u64* pub##c = pub + (size_t)(q + NQ * c) * 2 * NSL * T;
        DECL_CHAIN(0) DECL_CHAIN(1) DECL_CHAIN(2) DECL_CHAIN(3)
        #undef DECL_CHAIN

        auto CSTEP = [&](int s, int par, const float* fsP,
                         const float*& pp, const float*& qq,
                         float4& R0, float4& R1, float4& T1, u64* pubC) {
            float2 f = *(const float2*)&fsP[2 * rr];
            const u32 loA = tie24A | (u32)s;
            const u32 loB = loA - (1u << 24);
            auto mk = [&](float a0, float a1, float t1c) -> u64 {
                float vA = (f.x + t1c) + a0;     // exact ref order
                float vB = (f.y + t1c) + a1;
                bool  t  = vB > vA;              // strict >: lowest i on tie
                return ((u64)flipf(__float_as_uint(t ? vB : vA)) << 32)
                     | (t ? loB : loA);
            };
            u64 k0 = mk(R0.x, R1.x, T1.x);
            u64 k1 = mk(R0.y, R1.y, T1.y);
            u64 k2 = mk(R0.z, R1.z, T1.z);
            u64 k3 = mk(R0.w, R1.w, T1.w);

            // prefetch step s+2 into this now-dead set (2-step lead)
            if (s + 2 <= S) {
                pp += 2 * T * T;
                qq += 2 * T;
                R0 = *(const float4*)(pp);
                R1 = *(const float4*)(pp + T);
                T1 = *(const float4*)(qq);
            }

            auto red = [&](u64& kk) {
                u64 p;
                p = __shfl_xor(kk, 8,  64); if (p > kk) kk = p;
                p = __shfl_xor(kk, 16, 64); if (p > kk) kk = p;
                p = __shfl_xor(kk, 32, 64); if (p > kk) kk = p;
            };
            red(k0); red(k1); red(k2); red(k3);

            if (rr == 0) {
                u64* slot = pubC + ((size_t)par * NSL + k) * T + col0;
                astore(slot + 0, k0);
                astore(slot + 1, k1);
                astore(slot + 2, k2);
                astore(slot + 3, k3);
            }
        };

        for (int s = 1; s <= S; s += 2) {
            {   // odd step: set A, fs parity 0, pub parity 1
                const float* fsP = &fs_lds[(s + 1) & 1][0][0];
                CSTEP(s, s & 1, fsP + 0,  pA0, qA0, A00, A10, At0, pub0);
                CSTEP(s, s & 1, fsP + 16, pA1, qA1, A01, A11, At1, pub1);
                CSTEP(s, s & 1, fsP + 32, pA2, qA2, A02, A12, At2, pub2);
                CSTEP(s, s & 1, fsP + 48, pA3, qA3, A03, A13, At3, pub3);
            }
            bar_lds();
            {   // even step: set B
                const float* fsP = &fs_lds[s & 1][0][0];
                CSTEP(s + 1, (s + 1) & 1, fsP + 0,  pB0, qB0, B00, B10, Bt0, pub0);
                CSTEP(s + 1, (s + 1) & 1, fsP + 16, pB1, qB1, B01, B11, Bt1, pub1);
                CSTEP(s + 1, (s + 1) & 1, fsP + 32, pB2, qB2, B02, B12, Bt2, pub2);
                CSTEP(s + 1, (s + 1) & 1, fsP + 48, pB3, qB3, B03, B13, Bt3, pub3);
            }
            bar_lds();
        }
    } else {
        // ================= poller waves (no other VMEM) =================
        const int pw = wv - 4;               // 0: chains 0,1; 1: chains 2,3
        const int lr = ln >> 3;              // local row 0..7 (and +8)
        const int sl = ln & 7;               // source slice

        auto POLL = [&](int s, int par, int c) {
            const int b = q + NQ * c;
            const u64* base = pub + (size_t)b * 2 * NSL * T
                            + ((size_t)par * NSL + sl) * T + (k * 16 + lr);
            u64 v0, v1;
            for (;;) {
                v0 = aload(base);
                v1 = aload(base + 8);
                bool ok = ((u32)(v0 & 0xFFFFFFu) == (u32)s) &&
                          ((u32)(v1 & 0xFFFFFFu) == (u32)s);
                if (__all(ok)) break;
            }
            auto red = [&](u64& kk) {
                u64 p;
                p = __shfl_xor(kk, 1, 64); if (p > kk) kk = p;
                p = __shfl_xor(kk, 2, 64); if (p > kk) kk = p;
                p = __shfl_xor(kk, 4, 64); if (p > kk) kk = p;
            };
            red(v0); red(v1);
            if (sl == 0) {
                fs_lds[par][c][lr]     = __uint_as_float(unflipf((u32)(v0 >> 32)));
                fs_lds[par][c][lr + 8] = __uint_as_float(unflipf((u32)(v1 >> 32)));
                unsigned char* bpr = bp + ((size_t)b * S + (s - 1)) * T + k * 16;
                bpr[lr]     = (unsigned char)(127u - (((u32)(v0 >> 24)) & 0xFFu));
                bpr[lr + 8] = (unsigned char)(127u - (((u32)(v1 >> 24)) & 0xFFu));
            }
        };

        for (int s = 1; s <= S; s += 2) {
            POLL(s, s & 1, 2 * pw);
            POLL(s, s & 1, 2 * pw + 1);
            bar_lds();
            POLL(s + 1, (s + 1) & 1, 2 * pw);
            POLL(s + 1, (s + 1) & 1, 2 * pw + 1);
            bar_lds();
        }
    }
}

// ---------------- backtrack: one block per batch ---------------------------
__global__ __launch_bounds__(1024, 1)
void viterbi_bwd(const unsigned char* __restrict__ bp,
                 const int* __restrict__ eofp, int* __restrict__ out)
{
    __shared__ unsigned char lbp[S][T];  // 64 KB
    const int b   = blockIdx.x;
    const int tid = (int)threadIdx.x;

    const uint4* s4 = (const uint4*)(bp + (size_t)b * S * T);
    uint4* d4 = (uint4*)&lbp[0][0];
    #pragma unroll
    for (int it = 0; it < 4; ++it) d4[tid + it * 1024] = s4[tid + it * 1024];
    __syncthreads();

    if (tid == 0) {
        int ptr = lbp[S - 1][eofp[0]];
        for (int idx = S - 1; idx >= 0; --idx) {
            ptr = lbp[idx][ptr];
            out[(size_t)b * S + idx] = ptr;
        }
    }
}

// ---------------- fallback (proven R2 kernel) if ws too small --------------
__global__ __launch_bounds__(1024, 1)
void viterbi_fused_fb(const float* __restrict__ c0, const float* __restrict__ c1,
                      const int* __restrict__ sofp, const int* __restrict__ eofp,
                      int* __restrict__ out)
{
    __shared__ float fs[2][T];
    __shared__ float pmax[32][T];
    __shared__ int   parg[32][T];
    __shared__ unsigned char bpl[S][T];

    const int b   = blockIdx.x;
    const int tid = (int)threadIdx.x;
    const int jq  = tid & 31;
    const int gg2 = tid >> 5;
    const int col = jq * 4;
    const int row = gg2 * 4;

    const float* c0b = c0 + (size_t)b * (S + 1) * T * T;
    const float* c1b = c1 + (size_t)b * (S + 1) * T;

    if (tid < T) {
        const int sof = sofp[0];
        fs[0][tid] = c0b[(size_t)sof * T + tid] * c1b[tid];
    }
    __syncthreads();

    const float* t0p = c0b + (size_t)T * T;
    float4 a0 = *(const float4*)(t0p + (size_t)(row + 0) * T + col);
    float4 a1 = *(const float4*)(t0p + (size_t)(row + 1) * T + col);
    float4 a2 = *(const float4*)(t0p + (size_t)(row + 2) * T + col);
    float4 a3 = *(const float4*)(t0p + (size_t)(row + 3) * T + col);
    float4 tv = *(const float4*)(c1b + T + col);

    int p = 0;
    for (int s = 1; s <= S; ++s) {
        float4 b0 = make_float4(0.f,0.f,0.f,0.f), b1 = b0, b2 = b0, b3 = b0, bt = b0;
        if (s < S) {
            const float* n0 = c0b + (size_t)(s + 1) * T * T;
            b0 = *(const float4*)(n0 + (size_t)(row + 0) * T + col);
            b1 = *(const float4*)(n0 + (size_t)(row + 1) * T + col);
            b2 = *(const float4*)(n0 + (size_t)(row + 2) * T + col);
            b3 = *(const float4*)(n0 + (size_t)(row + 3) * T + col);
            bt = *(const float4*)(c1b + (size_t)(s + 1) * T + col);
        }
        const float f0 = fs[p][row + 0];
        const float f1 = fs[p][row + 1];
        const float f2 = fs[p][row + 2];
        const float f3 = fs[p][row + 3];

        float bx, by, bz, bw; int ix, iy, iz, iw; float v;
        bx = (f0 + tv.x) + a0.x; ix = row;
        by = (f0 + tv.y) + a0.y; iy = row;
        bz = (f0 + tv.z) + a0.z; iz = row;
        bw = (f0 + tv.w) + a0.w; iw = row;
        v = (f1 + tv.x) + a1.x; if (v > bx) { bx = v; ix = row + 1; }
        v = (f1 + tv.y) + a1.y; if (v > by) { by = v; iy = row + 1; }
        v = (f1 + tv.z) + a1.z; if (v > bz) { bz = v; iz = row + 1; }
        v = (f1 + tv.w) + a1.w; if (v > bw) { bw = v; iw = row + 1; }
        v = (f2 + tv.x) + a2.x; if (v > bx) { bx = v; ix = row + 2; }
        v = (f2 + tv.y) + a2.y; if (v > by) { by = v; iy = row + 2; }
        v = (f2 + tv.z) + a2.z; if (v > bz) { bz = v; iz = row + 2; }
        v = (f2 + tv.w) + a2.w; if (v > bw) { bw = v; iw = row + 2; }
        v = (f3 + tv.x) + a3.x; if (v > bx) { bx = v; ix = row + 3; }
        v = (f3 + tv.y) + a3.y; if (v > by) { by = v; iy = row + 3; }
        v = (f3 + tv.z) + a3.z; if (v > bz) { bz = v; iz = row + 3; }
        v = (f3 + tv.w) + a3.w; if (v > bw) { bw = v; iw = row + 3; }

        *(float4*)&pmax[gg2][col] = make_float4(bx, by, bz, bw);
        *(int4*)  &parg[gg2][col] = make_int4(ix, iy, iz, iw);
        __syncthreads();

        if (tid < T) {
            float bb = pmax[0][tid];
            int   ii = parg[0][tid];
            #pragma unroll
            for (int qq2 = 1; qq2 < 32; ++qq2) {
                float vv = pmax[qq2][tid];
                if (vv > bb) { bb = vv; ii = parg[qq2][tid]; }
            }
            fs[p ^ 1][tid] = bb;
            bpl[s - 1][tid] = (unsigned char)ii;
        }
        __syncthreads();
        p ^= 1;
        a0 = b0; a1 = b1; a2 = b2; a3 = b3; tv = bt;
    }

    if (tid == 0) {
        const int eof = eofp[0];
        int ptr = bpl[S - 1][eof];
        for (int idx = S - 1; idx >= 0; --idx) {
            ptr = bpl[idx][ptr];
            out[(size_t)b * S + idx] = ptr;
        }
    }
}

extern "C" void kernel_launch(void* const* d_in, const int* in_sizes, int n_in,
                              void* d_out, int out_size, void* d_ws, size_t ws_size,
                              hipStream_t stream)
{
    const float* c0  = (const float*)d_in[0];
    const float* c1  = (const float*)d_in[1];
    const int*   sof = (const int*)d_in[2];
    const int*   eof = (const int*)d_in[3];
    int*         out = (int*)d_out;

    const int B = in_sizes[1] / ((S + 1) * T);   // 32

    const size_t pub_b = (size_t)B * 2 * NSL * T * 8;   // 512 KB
    const size_t bp_b  = (size_t)B * S * T;             // 2 MB
    if (B == 32 && ws_size >= pub_b + bp_b) {
        u64* pubw = (u64*)d_ws;
        unsigned char* bpw = (unsigned char*)d_ws + pub_b;
        viterbi_fwd4<<<dim3(NSL * NQ), dim3(384), 0, stream>>>(c0, c1, sof, pubw, bpw);
        viterbi_bwd<<<dim3(B), dim3(1024), 0, stream>>>(bpw, eof, out);
    } else {
        viterbi_fused_fb<<<dim3(B), dim3(1024), 0, stream>>>(c0, c1, sof, eof, out);
    }
}

// Round 9
// 846.879 us; speedup vs baseline: 2.2853x; 2.2853x over previous
//
#include <hip/hip_runtime.h>

// Viterbi / CRF decode: B=32, S=512, T=128.
// R9: j-slice (column) decomposition. 256 blocks = 32 batches x 8 col-slices;
// block k owns columns k*16..k*16+15 and computes their new_fs/argmax over ALL
// 128 i locally each step -> published values are FINAL (no cross-block merge,
// argmax tie-break entirely local). Exchange = broadcast of 16 final values
// per block; consumers poll 112 remote values straight into fs_lds.
//
// Wave roles per block (256 thr):
//   waves 0-1 (tid<128): pollers ONLY - they issue no other VMEM after the
//     prologue, so each poll retry's vmcnt(0) waits only the poll load (clean
//     RT; fixes the R4/R8 prefetch-drain poisoning).
//   waves 2-3 (tid>=128): compute + stage. Col-slice t0[:,own 16 cols] is
//     staged to LDS via global_load_lds (double-buffered, 8 KB/step); each
//     thread scans 16 rows of one column; shfl_xor(16,32) + 2-key merge gives
//     the column's final max/argmax; 16 merge threads publish + write bp.
// Protocol (proven R4/R7): pub[b][parity][128] u64 = {fs_bits:32 | s:32};
// tag self-validates; parity slots safe (publish s+2 only after all consumed
// s); stale replay tags are never equal to the current s. Poison 0xAA.. != any
// tag. Correctness independent of block->XCD placement (agent scope).
// fp order exactly matches ref: (fs[i] + t1[j]) + t0[i,j]; first-max via
// ascending-i strict > locally + key tie byte (255-i) across threads.

constexpr int S   = 512;
constexpr int T   = 128;
constexpr int NSL = 8;     // column slices per batch
constexpr int CW  = 16;    // columns per slice

using u64 = unsigned long long;
using u32 = unsigned int;

__device__ __forceinline__ void bar_lds() {
    asm volatile("s_waitcnt lgkmcnt(0)" ::: "memory");
    __builtin_amdgcn_s_barrier();
}
__device__ __forceinline__ u32 flipf(u32 u)   { return u ^ (0x80000000u | (u32)((int)u >> 31)); }
__device__ __forceinline__ u32 unflipf(u32 y) { return y ^ (0x80000000u | ~(u32)((int)y >> 31)); }
__device__ __forceinline__ u64 aload(const u64* p) {
    return __hip_atomic_load(p, __ATOMIC_RELAXED, __HIP_MEMORY_SCOPE_AGENT);
}
__device__ __forceinline__ void astore(u64* p, u64 v) {
    __hip_atomic_store(p, v, __ATOMIC_RELAXED, __HIP_MEMORY_SCOPE_AGENT);
}

#define GLDS(srcp, dstp) \
    __builtin_amdgcn_global_load_lds( \
        (const __attribute__((address_space(1))) void*)(srcp), \
        (__attribute__((address_space(3))) void*)(dstp), 16, 0, 0)

__global__ __launch_bounds__(256, 1)
void viterbi_fwdj(const float* __restrict__ c0, const float* __restrict__ c1,
                  const int* __restrict__ sofp,
                  u64* __restrict__ pub,           // [32][2][128]
                  unsigned char* __restrict__ bp)  // [32][S][128]
{
    __shared__ float fs_lds[T];
    __shared__ float t0s[2][T * CW];   // staged col-slice, row-major [row][16]
    __shared__ u64   wpart[2][CW];     // per-compute-wave column partial keys

    const int g    = blockIdx.x;
    const int b    = g & 31;           // batch; g%8 = b%8 -> batch's blocks share XCD class
    const int k    = g >> 5;           // column slice 0..7
    const int tid  = (int)threadIdx.x;
    const int lane = tid & 63;

    const float* c0b = c0 + (size_t)b * (S + 1) * T * T;
    const float* c1b = c1 + (size_t)b * (S + 1) * T;
    u64* pubB = pub + (size_t)b * 2 * T;

    const bool is_cmp = tid >= 128;
    const int  ct  = tid - 128;        // compute index 0..127
    const int  j   = ct & 15;          // owned column (k*16 + j)
    const int  rb  = ct >> 4;          // row-block 0..7 (16 rows each)
    const int  wv2 = (tid >> 6) - 2;   // compute wave 0/1

    // Stage step ss's column slice t0[ss][:, k*16..+15] (8 KB) into t0s[buf].
    // Linear LDS dest (wave base + lane*16B); per-lane global source.
    auto STAGE = [&](int ss, int buf) {
        const float* srcbase = c0b + (size_t)ss * T * T + (size_t)k * CW;
        #pragma unroll
        for (int it = 0; it < 4; ++it) {
            const int q   = wv2 * 4 + it;            // 16-row chunk 0..7
            const int row = q * 16 + (lane >> 2);
            const float* src = srcbase + (size_t)row * T + (lane & 3) * 4;
            float* dst = &t0s[buf][q * 256];         // 16 rows * 16 cols
            GLDS(src, dst);
        }
    };

    // ---- prologue: local fs(0), stage s=1, t1(1) ----
    if (tid < T) fs_lds[tid] = c0b[(size_t)sofp[0] * T + tid] * c1b[tid];
    float t1c = 0.f, t1n = 0.f;
    if (is_cmp) {
        STAGE(1, 1);
        t1c = c1b[(size_t)1 * T + k * CW + j];
    }
    asm volatile("s_waitcnt vmcnt(0)" ::: "memory");
    bar_lds();

    for (int s = 1; s <= S; ++s) {
        const int par = s & 1;

        if (is_cmp) {
            // Column j: scan 16 rows (ascending i, strict > == first-max);
            // exact ref order (fs[i] + t1[j]) + t0[i,j].
            const float* tp = &t0s[par][0];
            const int r0 = rb * 16;
            u64 key;
            {
                float v = (fs_lds[r0] + t1c) + tp[r0 * CW + j];
                key = ((u64)flipf(__float_as_uint(v)) << 32) | (u32)(255 - r0);
            }
            #pragma unroll
            for (int r = 1; r < 16; ++r) {
                const int row = r0 + r;
                float v = (fs_lds[row] + t1c) + tp[row * CW + j];
                u64 kk = ((u64)flipf(__float_as_uint(v)) << 32) | (u32)(255 - row);
                if (kk > key) key = kk;      // unique tie byte: max == first-max
            }
            { u64 p = __shfl_xor(key, 16, 64); if (p > key) key = p; }
            { u64 p = __shfl_xor(key, 32, 64); if (p > key) key = p; }
            if ((ct & 63) < 16) wpart[wv2][j] = key;

            if (s < S) {
                STAGE(s + 1, par ^ 1);       // issue next staging early
                t1n = c1b[(size_t)(s + 1) * T + k * CW + j];
            }
        }
        bar_lds();   // A: wpart visible; remote pollers may now see our publish soon

        if (is_cmp && ct < 16) {
            // merge the two wave partials; publish FINAL value + bp + own fs.
            u64 kk = wpart[0][j];
            u64 k1 = wpart[1][j];
            if (k1 > kk) kk = k1;
            const u32 vb = unflipf((u32)(kk >> 32));
            const int ii = 255 - (int)(kk & 0xFFu);
            astore(&pubB[(size_t)par * T + k * CW + j], ((u64)vb << 32) | (u32)s);
            bp[((size_t)b * S + (s - 1)) * T + k * CW + j] = (unsigned char)ii;
            fs_lds[k * CW + j] = __uint_as_float(vb);
        }
        if (!is_cmp && (tid >> 4) != k) {
            // poller: one remote value; no other VMEM in flight -> clean RT.
            const u64* p = &pubB[(size_t)par * T + tid];
            u64 v;
            do { v = aload(p); } while ((u32)v != (u32)s);
            fs_lds[tid] = __uint_as_float((u32)(v >> 32));
        }
        if (is_cmp) asm volatile("s_waitcnt vmcnt(0)" ::: "memory");  // staging done
        bar_lds();   // B: fs(s) complete; t0s[par^1] valid

        t1c = t1n;
    }
}

// ---------------- backtrack: one block per batch ---------------------------
__global__ __launch_bounds__(1024, 1)
void viterbi_bwd(const unsigned char* __restrict__ bp,
                 const int* __restrict__ eofp, int* __restrict__ out)
{
    __shared__ unsigned char lbp[S][T];  // 64 KB
    const int b   = blockIdx.x;
    const int tid = (int)threadIdx.x;

    const uint4* s4 = (const uint4*)(bp + (size_t)b * S * T);
    uint4* d4 = (uint4*)&lbp[0][0];
    #pragma unroll
    for (int it = 0; it < 4; ++it) d4[tid + it * 1024] = s4[tid + it * 1024];
    __syncthreads();

    if (tid == 0) {
        int ptr = lbp[S - 1][eofp[0]];
        for (int idx = S - 1; idx >= 0; --idx) {
            ptr = lbp[idx][ptr];
            out[(size_t)b * S + idx] = ptr;
        }
    }
}

// ---------------- fallback (proven R2 kernel) if ws too small --------------
__global__ __launch_bounds__(1024, 1)
void viterbi_fused_fb(const float* __restrict__ c0, const float* __restrict__ c1,
                      const int* __restrict__ sofp, const int* __restrict__ eofp,
                      int* __restrict__ out)
{
    __shared__ float fs[2][T];
    __shared__ float pmax[32][T];
    __shared__ int   parg[32][T];
    __shared__ unsigned char bpl[S][T];

    const int b   = blockIdx.x;
    const int tid = (int)threadIdx.x;
    const int jq  = tid & 31;
    const int gg2 = tid >> 5;
    const int col = jq * 4;
    const int row = gg2 * 4;

    const float* c0b = c0 + (size_t)b * (S + 1) * T * T;
    const float* c1b = c1 + (size_t)b * (S + 1) * T;

    if (tid < T) {
        const int sof = sofp[0];
        fs[0][tid] = c0b[(size_t)sof * T + tid] * c1b[tid];
    }
    __syncthreads();

    const float* t0p = c0b + (size_t)T * T;
    float4 a0 = *(const float4*)(t0p + (size_t)(row + 0) * T + col);
    float4 a1 = *(const float4*)(t0p + (size_t)(row + 1) * T + col);
    float4 a2 = *(const float4*)(t0p + (size_t)(row + 2) * T + col);
    float4 a3 = *(const float4*)(t0p + (size_t)(row + 3) * T + col);
    float4 tv = *(const float4*)(c1b + T + col);

    int p = 0;
    for (int s = 1; s <= S; ++s) {
        float4 b0 = make_float4(0.f,0.f,0.f,0.f), b1 = b0, b2 = b0, b3 = b0, bt = b0;
        if (s < S) {
            const float* n0 = c0b + (size_t)(s + 1) * T * T;
            b0 = *(const float4*)(n0 + (size_t)(row + 0) * T + col);
            b1 = *(const float4*)(n0 + (size_t)(row + 1) * T + col);
            b2 = *(const float4*)(n0 + (size_t)(row + 2) * T + col);
            b3 = *(const float4*)(n0 + (size_t)(row + 3) * T + col);
            bt = *(const float4*)(c1b + (size_t)(s + 1) * T + col);
        }
        const float f0 = fs[p][row + 0];
        const float f1 = fs[p][row + 1];
        const float f2 = fs[p][row + 2];
        const float f3 = fs[p][row + 3];

        float bx, by, bz, bw; int ix, iy, iz, iw; float v;
        bx = (f0 + tv.x) + a0.x; ix = row;
        by = (f0 + tv.y) + a0.y; iy = row;
        bz = (f0 + tv.z) + a0.z; iz = row;
        bw = (f0 + tv.w) + a0.w; iw = row;
        v = (f1 + tv.x) + a1.x; if (v > bx) { bx = v; ix = row + 1; }
        v = (f1 + tv.y) + a1.y; if (v > by) { by = v; iy = row + 1; }
        v = (f1 + tv.z) + a1.z; if (v > bz) { bz = v; iz = row + 1; }
        v = (f1 + tv.w) + a1.w; if (v > bw) { bw = v; iw = row + 1; }
        v = (f2 + tv.x) + a2.x; if (v > bx) { bx = v; ix = row + 2; }
        v = (f2 + tv.y) + a2.y; if (v > by) { by = v; iy = row + 2; }
        v = (f2 + tv.z) + a2.z; if (v > bz) { bz = v; iz = row + 2; }
        v = (f2 + tv.w) + a2.w; if (v > bw) { bw = v; iw = row + 2; }
        v = (f3 + tv.x) + a3.x; if (v > bx) { bx = v; ix = row + 3; }
        v = (f3 + tv.y) + a3.y; if (v > by) { by = v; iy = row + 3; }
        v = (f3 + tv.z) + a3.z; if (v > bz) { bz = v; iz = row + 3; }
        v = (f3 + tv.w) + a3.w; if (v > bw) { bw = v; iw = row + 3; }

        *(float4*)&pmax[gg2][col] = make_float4(bx, by, bz, bw);
        *(int4*)  &parg[gg2][col] = make_int4(ix, iy, iz, iw);
        __syncthreads();

        if (tid < T) {
            float bb = pmax[0][tid];
            int   ii = parg[0][tid];
            #pragma unroll
            for (int qq2 = 1; qq2 < 32; ++qq2) {
                float vv = pmax[qq2][tid];
                if (vv > bb) { bb = vv; ii = parg[qq2][tid]; }
            }
            fs[p ^ 1][tid] = bb;
            bpl[s - 1][tid] = (unsigned char)ii;
        }
        __syncthreads();
        p ^= 1;
        a0 = b0; a1 = b1; a2 = b2; a3 = b3; tv = bt;
    }

    if (tid == 0) {
        const int eof = eofp[0];
        int ptr = bpl[S - 1][eof];
        for (int idx = S - 1; idx >= 0; --idx) {
            ptr = bpl[idx][ptr];
            out[(size_t)b * S + idx] = ptr;
        }
    }
}

extern "C" void kernel_launch(void* const* d_in, const int* in_sizes, int n_in,
                              void* d_out, int out_size, void* d_ws, size_t ws_size,
                              hipStream_t stream)
{
    const float* c0  = (const float*)d_in[0];
    const float* c1  = (const float*)d_in[1];
    const int*   sof = (const int*)d_in[2];
    const int*   eof = (const int*)d_in[3];
    int*         out = (int*)d_out;

    const int B = in_sizes[1] / ((S + 1) * T);   // 32

    const size_t pub_b = (size_t)B * 2 * T * 8;   // 64 KB
    const size_t bp_b  = (size_t)B * S * T;       // 2 MB
    if (B == 32 && ws_size >= pub_b + bp_b) {
        u64* pubw = (u64*)d_ws;
        unsigned char* bpw = (unsigned char*)d_ws + pub_b;
        viterbi_fwdj<<<dim3(B * NSL), dim3(256), 0, stream>>>(c0, c1, sof, pubw, bpw);
        viterbi_bwd<<<dim3(B), dim3(1024), 0, stream>>>(bpw, eof, out);
    } else {
        viterbi_fused_fb<<<dim3(B), dim3(1024), 0, stream>>>(c0, c1, sof, eof, out);
    }
}